// Round 1
// baseline (643.926 us; speedup 1.0000x reference)
//
#include <hip/hip_runtime.h>
#include <hip/hip_bf16.h>
#include <stdint.h>

typedef __attribute__((ext_vector_type(4))) float f32x4;
typedef __attribute__((ext_vector_type(8))) short short8v;
typedef __attribute__((ext_vector_type(8))) unsigned short ushort8v;

#define NB 8192
#define ND 2048
#define NE 8

__device__ __forceinline__ unsigned short f2bf(float f) {
    union { float f; uint32_t u; } c; c.f = f;
    uint32_t u = c.u;
    u = u + 0x7FFFu + ((u >> 16) & 1u);   // RNE
    return (unsigned short)(u >> 16);
}

// ---- convert W_experts fp32 -> bf16 ----
__global__ __launch_bounds__(256) void cvt_w_kernel(const float* __restrict__ W,
                                                    unsigned short* __restrict__ Wb) {
    size_t i = ((size_t)blockIdx.x * 256 + threadIdx.x) * 8;
    float4 a = *(const float4*)(W + i);
    float4 b = *(const float4*)(W + i + 4);
    ushort8v o;
    o[0] = f2bf(a.x); o[1] = f2bf(a.y); o[2] = f2bf(a.z); o[3] = f2bf(a.w);
    o[4] = f2bf(b.x); o[5] = f2bf(b.y); o[6] = f2bf(b.z); o[7] = f2bf(b.w);
    *(ushort8v*)(Wb + i) = o;
}

// ---- build inp = concat(x,y) as bf16 [NB][ND] ----
__global__ __launch_bounds__(256) void cvt_inp_kernel(const float* __restrict__ x,
                                                      const float* __restrict__ y,
                                                      unsigned short* __restrict__ inpb) {
    size_t i = ((size_t)blockIdx.x * 256 + threadIdx.x) * 8;
    int d = (int)(i & (ND - 1));
    size_t b = i >> 11;
    const float* src = (d < 1024) ? (x + b * 1024 + d) : (y + b * 1024 + (d - 1024));
    float4 a = *(const float4*)(src);
    float4 c = *(const float4*)(src + 4);
    ushort8v o;
    o[0] = f2bf(a.x); o[1] = f2bf(a.y); o[2] = f2bf(a.z); o[3] = f2bf(a.w);
    o[4] = f2bf(c.x); o[5] = f2bf(c.y); o[6] = f2bf(c.z); o[7] = f2bf(c.w);
    *(ushort8v*)(inpb + i) = o;
}

// ---- gate: fp64 logits, top-2 (torch.topk tie semantics), softmax ----
__global__ __launch_bounds__(256) void gate_kernel(const float* __restrict__ x,
                                                   const float* __restrict__ y,
                                                   const float* __restrict__ Wg,
                                                   const float* __restrict__ bg,
                                                   int* __restrict__ counts,
                                                   int* __restrict__ tkidx,
                                                   float* __restrict__ tkg) {
    const int wave = threadIdx.x >> 6, lane = threadIdx.x & 63;
    const int b = blockIdx.x * 4 + wave;
    double acc[NE] = {0, 0, 0, 0, 0, 0, 0, 0};
    for (int d = lane; d < ND; d += 64) {
        float v = (d < 1024) ? x[(size_t)b * 1024 + d] : y[(size_t)b * 1024 + d - 1024];
        double dv = (double)v;
#pragma unroll
        for (int e = 0; e < NE; e++) acc[e] += dv * (double)Wg[e * ND + d];
    }
#pragma unroll
    for (int e = 0; e < NE; e++) {
        double s = acc[e];
#pragma unroll
        for (int o = 32; o >= 1; o >>= 1) s += __shfl_xor(s, o, 64);
        acc[e] = s;
    }
    if (lane == 0) {
        double v0 = -1e300, v1 = -1e300; int i0 = 0, i1 = 1;
        for (int e = 0; e < NE; e++) {
            double val = acc[e] + (double)bg[e];
            if (val > v0)      { v1 = v0; i1 = i0; v0 = val; i0 = e; }
            else if (val > v1) { v1 = val; i1 = e; }
        }
        double e1 = exp(v1 - v0);
        double inv = 1.0 / (1.0 + e1);
        tkidx[b * 2]     = i0;
        tkidx[b * 2 + 1] = i1;
        tkg[b * 2]       = (float)inv;
        tkg[b * 2 + 1]   = (float)(e1 * inv);
        atomicAdd(&counts[i0], 1);
        atomicAdd(&counts[i1], 1);
    }
}

// ---- meta scan: offsets + cursors ----
__global__ void scan_kernel(int* meta) {
    if (threadIdx.x == 0) {
        int s = 0;
        for (int e = 0; e < NE; e++) { meta[8 + e] = s; meta[16 + e] = s; s += meta[e]; }
    }
}

// ---- fill per-expert token/gate lists ----
__global__ __launch_bounds__(256) void fill_kernel(const int* __restrict__ tkidx,
                                                   const float* __restrict__ tkg,
                                                   int* __restrict__ cursors,
                                                   int* __restrict__ tok,
                                                   float* __restrict__ gat) {
    const int b = blockIdx.x * 256 + threadIdx.x;
#pragma unroll
    for (int k = 0; k < 2; k++) {
        int e = tkidx[b * 2 + k];
        float g = tkg[b * 2 + k];
        int p = atomicAdd(&cursors[e], 1);
        tok[p] = b;
        gat[p] = g;
    }
}

#define GLD16(gp, lp) __builtin_amdgcn_global_load_lds( \
    (const __attribute__((address_space(1))) uint32_t*)(gp), \
    (__attribute__((address_space(3))) uint32_t*)(lp), 16, 0, 0)

// ---- grouped expert GEMM: C[rows(e), 2048] = A_gathered @ W_e^T, scatter-add with gates ----
__global__ __launch_bounds__(256) void moe_gemm_kernel(
    const unsigned short* __restrict__ Ab,   // [NB][ND] bf16
    const unsigned short* __restrict__ Wb,   // [NE][ND][ND] bf16 (out-major)
    const float* __restrict__ bias,          // [NE][ND]
    const int* __restrict__ tok,             // [2*NB] token ids, expert-bucketed
    const float* __restrict__ gat,           // [2*NB] gate weights
    const int* __restrict__ counts,          // meta[0..7]
    const int* __restrict__ offsets,         // meta[8..15]
    float* __restrict__ out)                 // [NB][ND] fp32, pre-zeroed
{
    const int e = blockIdx.z;
    const int cnt = counts[e];
    const int row0 = blockIdx.y * 128;
    if (row0 >= cnt) return;
    const int col0 = blockIdx.x * 128;
    const int base = offsets[e];

    __shared__ __align__(16) unsigned short As[128][32];
    __shared__ __align__(16) unsigned short Bs[128][32];

    const int tid  = threadIdx.x;
    const int wave = tid >> 6;
    const int lane = tid & 63;

    // staging geometry: per wave, 2 instrs for A (16 rows each) + 2 for B
    const int rA0 = wave * 16 + (lane >> 2);   // 0..63
    const int rA1 = 64 + rA0;                  // 64..127
    int gr0 = row0 + rA0; if (gr0 > cnt - 1) gr0 = cnt - 1;
    int gr1 = row0 + rA1; if (gr1 > cnt - 1) gr1 = cnt - 1;
    const int t0 = tok[base + gr0];
    const int t1 = tok[base + gr1];
    const unsigned short* aptr0 = Ab + (size_t)t0 * ND + (lane & 3) * 8;
    const unsigned short* aptr1 = Ab + (size_t)t1 * ND + (lane & 3) * 8;
    const unsigned short* wbase = Wb + (size_t)e * ND * ND;
    const unsigned short* bptr0 = wbase + (size_t)(col0 + rA0) * ND + (lane & 3) * 8;
    const unsigned short* bptr1 = wbase + (size_t)(col0 + rA1) * ND + (lane & 3) * 8;

    unsigned short* ldsA0 = &As[wave * 16][0];
    unsigned short* ldsA1 = &As[64 + wave * 16][0];
    unsigned short* ldsB0 = &Bs[wave * 16][0];
    unsigned short* ldsB1 = &Bs[64 + wave * 16][0];

    f32x4 acc[4][4];
#pragma unroll
    for (int m = 0; m < 4; m++)
#pragma unroll
        for (int n = 0; n < 4; n++) acc[m][n] = f32x4{0.f, 0.f, 0.f, 0.f};

    const int wr = wave >> 1, wc = wave & 1;   // 2x2 waves, 64x64 each
    const int fr = lane & 15;
    const int kh = lane >> 4;

    for (int kt = 0; kt < ND; kt += 32) {
        GLD16(aptr0 + kt, ldsA0);
        GLD16(aptr1 + kt, ldsA1);
        GLD16(bptr0 + kt, ldsB0);
        GLD16(bptr1 + kt, ldsB1);
        __syncthreads();
        short8v a_f[4], b_f[4];
#pragma unroll
        for (int m = 0; m < 4; m++)
            a_f[m] = *(const short8v*)&As[wr * 64 + m * 16 + fr][kh * 8];
#pragma unroll
        for (int n = 0; n < 4; n++)
            b_f[n] = *(const short8v*)&Bs[wc * 64 + n * 16 + fr][kh * 8];
#pragma unroll
        for (int m = 0; m < 4; m++)
#pragma unroll
            for (int n = 0; n < 4; n++)
                acc[m][n] = __builtin_amdgcn_mfma_f32_16x16x32_bf16(a_f[m], b_f[n], acc[m][n], 0, 0, 0);
        __syncthreads();
    }

    // epilogue: scatter-add gate-weighted (acc + bias) to out[token]
#pragma unroll
    for (int n = 0; n < 4; n++) {
        const int ccol = col0 + wc * 64 + n * 16 + fr;
        const float bv = bias[e * ND + ccol];
#pragma unroll
        for (int m = 0; m < 4; m++) {
#pragma unroll
            for (int j = 0; j < 4; j++) {
                const int R = row0 + wr * 64 + m * 16 + kh * 4 + j;
                if (R < cnt) {
                    const int t = tok[base + R];
                    const float g = gat[base + R];
                    atomicAdd(&out[(size_t)t * ND + ccol], g * (acc[m][n][j] + bv));
                }
            }
        }
    }
}

extern "C" void kernel_launch(void* const* d_in, const int* in_sizes, int n_in,
                              void* d_out, int out_size, void* d_ws, size_t ws_size,
                              hipStream_t stream) {
    const float* x  = (const float*)d_in[0];
    const float* y  = (const float*)d_in[1];
    const float* We = (const float*)d_in[2];
    const float* be = (const float*)d_in[3];
    const float* Wg = (const float*)d_in[4];
    const float* bg = (const float*)d_in[5];
    float* out = (float*)d_out;

    char* ws = (char*)d_ws;
    int*   meta  = (int*)ws;                              // [0..7] counts, [8..15] offsets, [16..23] cursors
    int*   tkidx = (int*)(ws + 1024);                     // [NB*2]
    float* tkg   = (float*)(ws + 1024 + 65536);           // [NB*2]
    int*   tok   = (int*)(ws + 1024 + 2 * 65536);         // [NB*2]
    float* gat   = (float*)(ws + 1024 + 3 * 65536);       // [NB*2]
    unsigned short* inpb = (unsigned short*)(ws + 1024 + 4 * 65536);
    unsigned short* wb   = (unsigned short*)(ws + 1024 + 4 * 65536 + (size_t)NB * ND * 2);

    hipMemsetAsync(meta, 0, 96, stream);
    hipMemsetAsync(d_out, 0, (size_t)NB * ND * sizeof(float), stream);
    cvt_w_kernel<<<16384, 256, 0, stream>>>(We, wb);
    cvt_inp_kernel<<<8192, 256, 0, stream>>>(x, y, inpb);
    gate_kernel<<<2048, 256, 0, stream>>>(x, y, Wg, bg, meta, tkidx, tkg);
    scan_kernel<<<1, 64, 0, stream>>>(meta);
    fill_kernel<<<32, 256, 0, stream>>>(tkidx, tkg, meta + 16, tok, gat);
    moe_gemm_kernel<<<dim3(16, 128, 8), 256, 0, stream>>>(inpb, wb, be, tok, gat, meta, meta + 8, out);
}

// Round 2
// 381.965 us; speedup vs baseline: 1.6858x; 1.6858x over previous
//
#include <hip/hip_runtime.h>
#include <stdint.h>

typedef __attribute__((ext_vector_type(4))) float f32x4;
typedef __attribute__((ext_vector_type(8))) short short8v;
typedef __attribute__((ext_vector_type(8))) unsigned short ushort8v;
typedef __attribute__((ext_vector_type(4))) unsigned short ushort4v;

#define NB 8192
#define ND 2048
#define NE 8

__device__ __forceinline__ unsigned short f2bf(float f) {
    union { float f; uint32_t u; } c; c.f = f;
    uint32_t u = c.u;
    u = u + 0x7FFFu + ((u >> 16) & 1u);   // RNE
    return (unsigned short)(u >> 16);
}

// ---- convert W_experts fp32 -> bf16 (134 MB read + 67 MB write, ~35 us) ----
__global__ __launch_bounds__(256) void cvt_w_kernel(const float* __restrict__ W,
                                                    unsigned short* __restrict__ Wb) {
    size_t i = ((size_t)blockIdx.x * 256 + threadIdx.x) * 8;
    float4 a = *(const float4*)(W + i);
    float4 b = *(const float4*)(W + i + 4);
    ushort8v o;
    o[0] = f2bf(a.x); o[1] = f2bf(a.y); o[2] = f2bf(a.z); o[3] = f2bf(a.w);
    o[4] = f2bf(b.x); o[5] = f2bf(b.y); o[6] = f2bf(b.z); o[7] = f2bf(b.w);
    *(ushort8v*)(Wb + i) = o;
}

// ---- fused: inp=concat(x,y)->bf16  +  fp64 gate logits -> top2 + softmax ----
// one wave per token; NO global atomics (counts done later by ballot hist)
__global__ __launch_bounds__(256) void gatecvt_kernel(const float* __restrict__ x,
                                                      const float* __restrict__ y,
                                                      const float* __restrict__ Wg,
                                                      const float* __restrict__ bg,
                                                      unsigned short* __restrict__ inpb,
                                                      int* __restrict__ tkidx,
                                                      float* __restrict__ tkg) {
    const int wave = threadIdx.x >> 6, lane = threadIdx.x & 63;
    const int b = blockIdx.x * 4 + wave;
    const float* xb = x + (size_t)b * 1024;
    const float* yb = y + (size_t)b * 1024;
    unsigned short* ob = inpb + (size_t)b * ND;
    double acc[NE] = {0, 0, 0, 0, 0, 0, 0, 0};
#pragma unroll
    for (int it = 0; it < 8; it++) {
        const int d = it * 256 + lane * 4;
        float4 v = (it < 4) ? *(const float4*)(xb + d) : *(const float4*)(yb + (d - 1024));
        ushort4v o;
        o[0] = f2bf(v.x); o[1] = f2bf(v.y); o[2] = f2bf(v.z); o[3] = f2bf(v.w);
        *(ushort4v*)(ob + d) = o;
#pragma unroll
        for (int e = 0; e < NE; e++) {
            float4 w = *(const float4*)(Wg + e * ND + d);
            acc[e] += (double)v.x * (double)w.x + (double)v.y * (double)w.y
                    + (double)v.z * (double)w.z + (double)v.w * (double)w.w;
        }
    }
#pragma unroll
    for (int e = 0; e < NE; e++) {
        double s = acc[e];
#pragma unroll
        for (int o = 32; o >= 1; o >>= 1) s += __shfl_xor(s, o, 64);
        acc[e] = s;
    }
    if (lane == 0) {
        double v0 = -1e300, v1 = -1e300; int i0 = 0, i1 = 1;
#pragma unroll
        for (int e = 0; e < NE; e++) {
            double val = acc[e] + (double)bg[e];
            if (val > v0)      { v1 = v0; i1 = i0; v0 = val; i0 = e; }
            else if (val > v1) { v1 = val; i1 = e; }
        }
        double e1 = exp(v1 - v0);
        double inv = 1.0 / (1.0 + e1);
        tkidx[b * 2]     = i0;
        tkidx[b * 2 + 1] = i1;
        tkg[b * 2]       = (float)inv;
        tkg[b * 2 + 1]   = (float)(e1 * inv);
    }
}

// ---- per-chunk histogram via ballot (64 chunks x 256 pairs), deterministic ----
__global__ __launch_bounds__(256) void hist_kernel(const int* __restrict__ tkidx,
                                                   int* __restrict__ hist) {
    const int p = blockIdx.x * 256 + threadIdx.x;
    const int wave = threadIdx.x >> 6, lane = threadIdx.x & 63;
    const int e = tkidx[p];
    __shared__ int cnt[4][8];
#pragma unroll
    for (int e2 = 0; e2 < 8; e2++) {
        unsigned long long m = __ballot(e == e2);
        if (lane == e2) cnt[wave][e2] = __popcll(m);
    }
    __syncthreads();
    if (threadIdx.x < 8)
        hist[blockIdx.x * 8 + threadIdx.x] =
            cnt[0][threadIdx.x] + cnt[1][threadIdx.x] + cnt[2][threadIdx.x] + cnt[3][threadIdx.x];
}

// ---- scan: chunk bases + expert totals/offsets ----
__global__ void scan_kernel(const int* __restrict__ hist, int* __restrict__ chunkbase,
                            int* __restrict__ meta) {
    __shared__ int total[8], off[8];
    const int t = threadIdx.x;
    if (t < 8) {
        int run = 0;
        for (int c = 0; c < 64; c++) { chunkbase[c * 8 + t] = run; run += hist[c * 8 + t]; }
        total[t] = run; meta[t] = run;
    }
    __syncthreads();
    if (t == 0) { int o = 0; for (int e = 0; e < 8; e++) { off[e] = o; meta[8 + e] = o; o += total[e]; } }
    __syncthreads();
    for (int i = t; i < 512; i += 64) chunkbase[i] += off[i & 7];
}

// ---- fill: stable rank within (chunk,expert) via ballot, no atomics ----
__global__ __launch_bounds__(256) void fill_kernel(const int* __restrict__ tkidx,
                                                   const float* __restrict__ tkg,
                                                   const int* __restrict__ chunkbase,
                                                   int* __restrict__ tok,
                                                   float* __restrict__ gat) {
    const int p = blockIdx.x * 256 + threadIdx.x;
    const int wave = threadIdx.x >> 6, lane = threadIdx.x & 63;
    const int e = tkidx[p];
    const float g = tkg[p];
    __shared__ int cnt[4][8];
    unsigned long long mym = 0;
#pragma unroll
    for (int e2 = 0; e2 < 8; e2++) {
        unsigned long long m = __ballot(e == e2);
        if (e == e2) mym = m;
        if (lane == e2) cnt[wave][e2] = __popcll(m);
    }
    __syncthreads();
    int basep = chunkbase[blockIdx.x * 8 + e];
    for (int w = 0; w < wave; w++) basep += cnt[w][e];
    const int rank = __popcll(mym & ((1ull << lane) - 1ull));
    tok[basep + rank] = p >> 1;
    gat[basep + rank] = g;
}

#define GLD16(gp, lp) __builtin_amdgcn_global_load_lds( \
    (const __attribute__((address_space(1))) uint32_t*)(gp), \
    (__attribute__((address_space(3))) uint32_t*)(lp), 16, 0, 0)

// ---- grouped expert GEMM: 256x256 tile, BK=64, 8 waves (2Mx4N), T2 swizzle ----
__global__ __launch_bounds__(512, 2) void moe_gemm_kernel(
    const unsigned short* __restrict__ Ab,   // [NB][ND] bf16
    const unsigned short* __restrict__ Wb,   // [NE][ND][ND] bf16 (out-major)
    const float* __restrict__ bias,          // [NE][ND]
    const int* __restrict__ tok,             // [2*NB] token ids, expert-bucketed
    const float* __restrict__ gat,           // [2*NB] gate weights
    const int* __restrict__ meta,            // [0..7] counts, [8..15] offsets
    float* __restrict__ out)                 // [NB][ND] fp32, pre-zeroed
{
    const int e = blockIdx.z;
    const int cnt = meta[e];
    const int row0 = blockIdx.y * 256;
    if (row0 >= cnt) return;
    const int col0 = blockIdx.x * 256;
    const int base = meta[8 + e];

    __shared__ __align__(16) unsigned short As[256][64];   // 32 KB
    __shared__ __align__(16) unsigned short Bs[256][64];   // 32 KB

    const int tid  = threadIdx.x;
    const int wv   = tid >> 6;     // 0..7
    const int lane = tid & 63;

    // --- staging geometry: 4 rounds each for A/B; round i covers rows i*64+srow
    // LDS dest is LINEAR (wave-uniform base + lane*16); the SOURCE chunk is
    // inverse-swizzled so reads can XOR-swizzle (rule 21: both-sides-or-neither)
    const int srow = wv * 8 + (lane >> 3);            // 0..63 within round
    const int cg   = (lane & 7) ^ (srow & 7);         // swizzled global chunk
    const unsigned short* wbase = Wb + (size_t)e * ND * ND;
    const unsigned short* asrc[4];
    const unsigned short* bsrc[4];
#pragma unroll
    for (int i = 0; i < 4; i++) {
        const int r = i * 64 + srow;
        int gr = row0 + r; if (gr > cnt - 1) gr = cnt - 1;
        asrc[i] = Ab + (size_t)tok[base + gr] * ND + cg * 8;
        bsrc[i] = wbase + (size_t)(col0 + r) * ND + cg * 8;
    }
    char* ldsA = (char*)&As[0][0] + wv * 1024 + (size_t)lane * 16;
    char* ldsB = (char*)&Bs[0][0] + wv * 1024 + (size_t)lane * 16;

    f32x4 acc[8][4];
#pragma unroll
    for (int m = 0; m < 8; m++)
#pragma unroll
        for (int n = 0; n < 4; n++) acc[m][n] = f32x4{0.f, 0.f, 0.f, 0.f};

    const int wr = wv >> 2, wcn = wv & 3;   // wave tile: rows wr*128.., cols wcn*64..
    const int fr = lane & 15;
    const int kh = lane >> 4;               // 0..3
    int ca[2];
#pragma unroll
    for (int ks = 0; ks < 2; ks++) ca[ks] = ((ks * 4 + kh) ^ (fr & 7)) * 8;  // swizzled read col (shorts)

    for (int kt = 0; kt < ND; kt += 64) {
#pragma unroll
        for (int i = 0; i < 4; i++) {
            GLD16(asrc[i] + kt, ldsA + i * 8192);
            GLD16(bsrc[i] + kt, ldsB + i * 8192);
        }
        __syncthreads();   // compiler drains vmcnt before barrier
#pragma unroll
        for (int ks = 0; ks < 2; ks++) {
            short8v a_f[8], b_f[4];
#pragma unroll
            for (int m = 0; m < 8; m++)
                a_f[m] = *(const short8v*)&As[wr * 128 + m * 16 + fr][ca[ks]];
#pragma unroll
            for (int n = 0; n < 4; n++)
                b_f[n] = *(const short8v*)&Bs[wcn * 64 + n * 16 + fr][ca[ks]];
#pragma unroll
            for (int m = 0; m < 8; m++)
#pragma unroll
                for (int n = 0; n < 4; n++)
                    acc[m][n] = __builtin_amdgcn_mfma_f32_16x16x32_bf16(a_f[m], b_f[n], acc[m][n], 0, 0, 0);
        }
        __syncthreads();
    }

    // --- epilogue: gate-weighted scatter-add (exactly 2 adds/output element) ---
    float bv[4];
#pragma unroll
    for (int n = 0; n < 4; n++) bv[n] = bias[e * ND + col0 + wcn * 64 + n * 16 + fr];
#pragma unroll
    for (int m = 0; m < 8; m++) {
        const int rbase = row0 + wr * 128 + m * 16 + kh * 4;
#pragma unroll
        for (int j = 0; j < 4; j++) {
            const int R = rbase + j;
            if (R < cnt) {
                const int t = tok[base + R];
                const float g = gat[base + R];
                float* orow = out + (size_t)t * ND + col0 + wcn * 64 + fr;
#pragma unroll
                for (int n = 0; n < 4; n++)
                    atomicAdd(orow + n * 16, g * (acc[m][n][j] + bv[n]));
            }
        }
    }
}

extern "C" void kernel_launch(void* const* d_in, const int* in_sizes, int n_in,
                              void* d_out, int out_size, void* d_ws, size_t ws_size,
                              hipStream_t stream) {
    const float* x  = (const float*)d_in[0];
    const float* y  = (const float*)d_in[1];
    const float* We = (const float*)d_in[2];
    const float* be = (const float*)d_in[3];
    const float* Wg = (const float*)d_in[4];
    const float* bg = (const float*)d_in[5];
    float* out = (float*)d_out;

    char* ws = (char*)d_ws;
    int*   meta  = (int*)ws;                               // [0..7] counts, [8..15] offsets
    int*   hist  = (int*)(ws + 256);                       // [64*8]
    int*   cbase = (int*)(ws + 256 + 2048);                // [64*8]
    int*   tkidx = (int*)(ws + 8192);                      // [NB*2]
    float* tkg   = (float*)(ws + 8192 + 65536);            // [NB*2]
    int*   tok   = (int*)(ws + 8192 + 2 * 65536);          // [NB*2]
    float* gat   = (float*)(ws + 8192 + 3 * 65536);        // [NB*2]
    unsigned short* inpb = (unsigned short*)(ws + 8192 + 4 * 65536);
    unsigned short* wb   = (unsigned short*)(ws + 8192 + 4 * 65536 + (size_t)NB * ND * 2);

    hipMemsetAsync(d_out, 0, (size_t)NB * ND * sizeof(float), stream);
    cvt_w_kernel<<<16384, 256, 0, stream>>>(We, wb);
    gatecvt_kernel<<<2048, 256, 0, stream>>>(x, y, Wg, bg, inpb, tkidx, tkg);
    hist_kernel<<<64, 256, 0, stream>>>(tkidx, hist);
    scan_kernel<<<1, 64, 0, stream>>>(hist, cbase, meta);
    fill_kernel<<<64, 256, 0, stream>>>(tkidx, tkg, cbase, tok, gat);
    moe_gemm_kernel<<<dim3(8, 64, 8), 512, 0, stream>>>(inpb, wb, be, tok, gat, meta, out);
}

// Round 4
// 358.719 us; speedup vs baseline: 1.7951x; 1.0648x over previous
//
#include <hip/hip_runtime.h>
#include <stdint.h>

typedef __attribute__((ext_vector_type(4))) float f32x4;
typedef __attribute__((ext_vector_type(8))) short short8v;
typedef __attribute__((ext_vector_type(8))) unsigned short ushort8v;
typedef __attribute__((ext_vector_type(4))) unsigned short ushort4v;

#define NB 8192
#define ND 2048
#define NE 8
#define NT 32   // K-tiles of 64

__device__ __forceinline__ unsigned short f2bf(float f) {
    union { float f; uint32_t u; } c; c.f = f;
    uint32_t u = c.u;
    u = u + 0x7FFFu + ((u >> 16) & 1u);   // RNE
    return (unsigned short)(u >> 16);
}

// ---- convert W_experts fp32 -> bf16 ----
__global__ __launch_bounds__(256) void cvt_w_kernel(const float* __restrict__ W,
                                                    unsigned short* __restrict__ Wb) {
    size_t i = ((size_t)blockIdx.x * 256 + threadIdx.x) * 8;
    float4 a = *(const float4*)(W + i);
    float4 b = *(const float4*)(W + i + 4);
    ushort8v o;
    o[0] = f2bf(a.x); o[1] = f2bf(a.y); o[2] = f2bf(a.z); o[3] = f2bf(a.w);
    o[4] = f2bf(b.x); o[5] = f2bf(b.y); o[6] = f2bf(b.z); o[7] = f2bf(b.w);
    *(ushort8v*)(Wb + i) = o;
}

// ---- fused: inp=concat(x,y)->bf16  +  fp64 gate logits -> top2 + softmax ----
__global__ __launch_bounds__(256) void gatecvt_kernel(const float* __restrict__ x,
                                                      const float* __restrict__ y,
                                                      const float* __restrict__ Wg,
                                                      const float* __restrict__ bg,
                                                      unsigned short* __restrict__ inpb,
                                                      int* __restrict__ tkidx,
                                                      float* __restrict__ tkg) {
    const int wave = threadIdx.x >> 6, lane = threadIdx.x & 63;
    const int b = blockIdx.x * 4 + wave;
    const float* xb = x + (size_t)b * 1024;
    const float* yb = y + (size_t)b * 1024;
    unsigned short* ob = inpb + (size_t)b * ND;
    double acc[NE] = {0, 0, 0, 0, 0, 0, 0, 0};
#pragma unroll
    for (int it = 0; it < 8; it++) {
        const int d = it * 256 + lane * 4;
        float4 v = (it < 4) ? *(const float4*)(xb + d) : *(const float4*)(yb + (d - 1024));
        ushort4v o;
        o[0] = f2bf(v.x); o[1] = f2bf(v.y); o[2] = f2bf(v.z); o[3] = f2bf(v.w);
        *(ushort4v*)(ob + d) = o;
#pragma unroll
        for (int e = 0; e < NE; e++) {
            float4 w = *(const float4*)(Wg + e * ND + d);
            acc[e] += (double)v.x * (double)w.x + (double)v.y * (double)w.y
                    + (double)v.z * (double)w.z + (double)v.w * (double)w.w;
        }
    }
#pragma unroll
    for (int e = 0; e < NE; e++) {
        double s = acc[e];
#pragma unroll
        for (int o = 32; o >= 1; o >>= 1) s += __shfl_xor(s, o, 64);
        acc[e] = s;
    }
    if (lane == 0) {
        double v0 = -1e300, v1 = -1e300; int i0 = 0, i1 = 1;
#pragma unroll
        for (int e = 0; e < NE; e++) {
            double val = acc[e] + (double)bg[e];
            if (val > v0)      { v1 = v0; i1 = i0; v0 = val; i0 = e; }
            else if (val > v1) { v1 = val; i1 = e; }
        }
        double e1 = exp(v1 - v0);
        double inv = 1.0 / (1.0 + e1);
        tkidx[b * 2]     = i0;
        tkidx[b * 2 + 1] = i1;
        tkg[b * 2]       = (float)inv;
        tkg[b * 2 + 1]   = (float)(e1 * inv);
    }
}

// ---- per-chunk histogram via ballot (64 chunks x 256 pairs), deterministic ----
__global__ __launch_bounds__(256) void hist_kernel(const int* __restrict__ tkidx,
                                                   int* __restrict__ hist) {
    const int p = blockIdx.x * 256 + threadIdx.x;
    const int wave = threadIdx.x >> 6, lane = threadIdx.x & 63;
    const int e = tkidx[p];
    __shared__ int cnt[4][8];
#pragma unroll
    for (int e2 = 0; e2 < 8; e2++) {
        unsigned long long m = __ballot(e == e2);
        if (lane == e2) cnt[wave][e2] = __popcll(m);
    }
    __syncthreads();
    if (threadIdx.x < 8)
        hist[blockIdx.x * 8 + threadIdx.x] =
            cnt[0][threadIdx.x] + cnt[1][threadIdx.x] + cnt[2][threadIdx.x] + cnt[3][threadIdx.x];
}

// ---- scan: chunk bases + expert totals/offsets ----
__global__ void scan_kernel(const int* __restrict__ hist, int* __restrict__ chunkbase,
                            int* __restrict__ meta) {
    __shared__ int total[8], off[8];
    const int t = threadIdx.x;
    if (t < 8) {
        int run = 0;
        for (int c = 0; c < 64; c++) { chunkbase[c * 8 + t] = run; run += hist[c * 8 + t]; }
        total[t] = run; meta[t] = run;
    }
    __syncthreads();
    if (t == 0) { int o = 0; for (int e = 0; e < 8; e++) { off[e] = o; meta[8 + e] = o; o += total[e]; } }
    __syncthreads();
    for (int i = t; i < 512; i += 64) chunkbase[i] += off[i & 7];
}

// ---- fill: stable rank within (chunk,expert) via ballot, no atomics ----
__global__ __launch_bounds__(256) void fill_kernel(const int* __restrict__ tkidx,
                                                   const float* __restrict__ tkg,
                                                   const int* __restrict__ chunkbase,
                                                   int* __restrict__ tok,
                                                   float* __restrict__ gat) {
    const int p = blockIdx.x * 256 + threadIdx.x;
    const int wave = threadIdx.x >> 6, lane = threadIdx.x & 63;
    const int e = tkidx[p];
    const float g = tkg[p];
    __shared__ int cnt[4][8];
    unsigned long long mym = 0;
#pragma unroll
    for (int e2 = 0; e2 < 8; e2++) {
        unsigned long long m = __ballot(e == e2);
        if (e == e2) mym = m;
        if (lane == e2) cnt[wave][e2] = __popcll(m);
    }
    __syncthreads();
    int basep = chunkbase[blockIdx.x * 8 + e];
    for (int w = 0; w < wave; w++) basep += cnt[w][e];
    const int rank = __popcll(mym & ((1ull << lane) - 1ull));
    tok[basep + rank] = p >> 1;
    gat[basep + rank] = g;
}

#define GLD16(gp, lp) __builtin_amdgcn_global_load_lds( \
    (const __attribute__((address_space(1))) uint32_t*)(gp), \
    (__attribute__((address_space(3))) uint32_t*)(lp), 16, 0, 0)

// ================= grouped expert GEMM, 8-phase counted-vmcnt schedule =================
// 256x256 tile, BK=64, 8 waves (2M x 4N). LDS: 2 bufs x 4 half-slots (A0,A1,B0,B1) 16KB.
// Wave-interleaved output mapping so phase (PM,PN) reads exactly A-half PM + B-half PN:
//   row(m) = (m>>2)*128 + wr*64 + (m&3)*16 ; col(n) = (n>>1)*128 + wcn*32 + (n&1)*16
// Quadrant order (0,0),(1,0),(0,1),(1,1): last reads B0@p1, A0@p2, A1@p3, B1@p3.
// Stage schedule for tile T: B0@p2(T-2), A0@p3(T-2), A1@p0(T-1), B1@p1(T-1).
// Per-tile checkpoint vmcnt(6) guarantees B0,A0,A1 landed; B1 has 5-phase slack.
__global__ __launch_bounds__(512, 2) void moe_gemm_kernel(
    const unsigned short* __restrict__ Ab,   // [NB][ND] bf16
    const unsigned short* __restrict__ Wb,   // [NE][ND][ND] bf16 (out-major)
    const float* __restrict__ bias,          // [NE][ND]
    const int* __restrict__ tok,             // [2*NB] token ids, expert-bucketed
    const float* __restrict__ gat,           // [2*NB] gate weights
    const int* __restrict__ meta,            // [0..7] counts, [8..15] offsets
    float* __restrict__ out)                 // [NB][ND] fp32, pre-zeroed
{
    const int e = blockIdx.z;
    const int cnt = meta[e];
    const int row0 = blockIdx.y * 256;
    if (row0 >= cnt) return;
    const int col0 = blockIdx.x * 256;
    const int base = meta[8 + e];

    // [buf][half: 0=A0 1=A1 2=B0 3=B1][128 rows][64 cols] = 128 KB
    __shared__ __align__(16) unsigned short S[2][4][128][64];

    const int tid  = threadIdx.x;
    const int wv   = tid >> 6;
    const int lane = tid & 63;
    const int wr = wv >> 2, wcn = wv & 3;
    const int fr = lane & 15, kh = lane >> 4;

    // --- staging source pointers (linear LDS dest + inverse-swizzled global chunk)
    const int srow = tid >> 3;                         // 0..63 per round
    const int cg8  = ((tid & 7) ^ (srow & 7)) * 8;     // swizzled source chunk (shorts)
    const unsigned short* wbase = Wb + (size_t)e * ND * ND;
    const unsigned short* aptr[2][2];
    const unsigned short* bptr[2][2];
#pragma unroll
    for (int h = 0; h < 2; h++)
#pragma unroll
        for (int i = 0; i < 2; i++) {
            int rt = h * 128 + i * 64 + srow;
            int gr = row0 + rt; if (gr > cnt - 1) gr = cnt - 1;
            aptr[h][i] = Ab + (size_t)tok[base + gr] * ND + cg8;
            bptr[h][i] = wbase + (size_t)(col0 + rt) * ND + cg8;
        }

#define STAGE_A(SB, SM, SK) do { \
    GLD16(aptr[SM][0] + (SK), (char*)&S[SB][SM][0][0] + tid * 16); \
    GLD16(aptr[SM][1] + (SK), (char*)&S[SB][SM][0][0] + tid * 16 + 8192); } while (0)
#define STAGE_B(SB, SN, SK) do { \
    GLD16(bptr[SN][0] + (SK), (char*)&S[SB][2 + SN][0][0] + tid * 16); \
    GLD16(bptr[SN][1] + (SK), (char*)&S[SB][2 + SN][0][0] + tid * 16 + 8192); } while (0)

    f32x4 acc[8][4];
#pragma unroll
    for (int m = 0; m < 8; m++)
#pragma unroll
        for (int n = 0; n < 4; n++) acc[m][n] = f32x4{0.f, 0.f, 0.f, 0.f};

    const int arow = wr * 64 + fr;        // + ml*16 within half
    const int brow = wcn * 32 + fr;       // + nl*16 within half
    int ca[2];
#pragma unroll
    for (int ks = 0; ks < 2; ks++) ca[ks] = ((ks * 4 + kh) ^ (fr & 7)) * 8;

#define PHASE(PB, PM, PN, ...) do { \
    short8v ar[4][2], br[2][2]; \
    _Pragma("unroll") \
    for (int ks = 0; ks < 2; ks++) { \
        _Pragma("unroll") \
        for (int ml = 0; ml < 4; ml++) \
            ar[ml][ks] = *(const short8v*)&S[PB][PM][arow + ml * 16][ca[ks]]; \
        _Pragma("unroll") \
        for (int nl = 0; nl < 2; nl++) \
            br[nl][ks] = *(const short8v*)&S[PB][2 + PN][brow + nl * 16][ca[ks]]; \
    } \
    __VA_ARGS__; \
    __builtin_amdgcn_sched_barrier(0); \
    __builtin_amdgcn_s_barrier(); \
    asm volatile("s_waitcnt lgkmcnt(0)" ::: "memory"); \
    __builtin_amdgcn_sched_barrier(0); \
    __builtin_amdgcn_s_setprio(1); \
    _Pragma("unroll") \
    for (int ks = 0; ks < 2; ks++) \
        _Pragma("unroll") \
        for (int ml = 0; ml < 4; ml++) \
            _Pragma("unroll") \
            for (int nl = 0; nl < 2; nl++) \
                acc[PM * 4 + ml][PN * 2 + nl] = __builtin_amdgcn_mfma_f32_16x16x32_bf16( \
                    ar[ml][ks], br[nl][ks], acc[PM * 4 + ml][PN * 2 + nl], 0, 0, 0); \
    __builtin_amdgcn_s_setprio(0); \
    __builtin_amdgcn_sched_barrier(0); \
    __builtin_amdgcn_s_barrier(); \
} while (0)

    // --- prologue: tile0 all halves + tile1 B0,A0; guarantee tile0 landed
    STAGE_B(0, 0, 0);
    STAGE_A(0, 0, 0);
    STAGE_A(0, 1, 0);
    STAGE_B(0, 1, 0);
    STAGE_B(1, 0, 64);
    STAGE_A(1, 0, 64);
    asm volatile("s_waitcnt vmcnt(4)" ::: "memory");
    __builtin_amdgcn_sched_barrier(0);
    __builtin_amdgcn_s_barrier();

    int buf = 0;
    for (int t = 0; t < NT; t++) {
        const int nb = buf ^ 1;
        const int kt1 = (t + 1) * 64;
        const int kt2 = (t + 2) * 64;
        PHASE(buf, 0, 0, { if (t + 1 < NT) STAGE_A(nb, 1, kt1); });   // reads A0,B0
        PHASE(buf, 1, 0, { if (t + 1 < NT) STAGE_B(nb, 1, kt1); });   // reads A1,B0
        PHASE(buf, 0, 1, { if (t + 2 < NT) STAGE_B(buf, 0, kt2); });  // reads A0,B1
        PHASE(buf, 1, 1, { if (t + 2 < NT) STAGE_A(buf, 0, kt2); });  // reads A1,B1
        if (t + 1 < NT) {
            if (t == NT - 2) asm volatile("s_waitcnt vmcnt(0)" ::: "memory");
            else             asm volatile("s_waitcnt vmcnt(6)" ::: "memory");
            __builtin_amdgcn_sched_barrier(0);
            __builtin_amdgcn_s_barrier();
        }
        buf = nb;
    }

    // --- epilogue: gate-weighted scatter-add (exactly 2 adds/output element) ---
    int   coln[4];
    float bv[4];
#pragma unroll
    for (int n = 0; n < 4; n++) {
        coln[n] = col0 + (n >> 1) * 128 + wcn * 32 + (n & 1) * 16 + fr;
        bv[n] = bias[e * ND + coln[n]];
    }
#pragma unroll
    for (int m = 0; m < 8; m++) {
        const int rbase = row0 + (m >> 2) * 128 + wr * 64 + (m & 3) * 16 + kh * 4;
#pragma unroll
        for (int j = 0; j < 4; j++) {
            const int R = rbase + j;
            if (R < cnt) {
                const int tkn = tok[base + R];
                const float g = gat[base + R];
                float* orow = out + (size_t)tkn * ND;
#pragma unroll
                for (int n = 0; n < 4; n++)
                    atomicAdd(orow + coln[n], g * (acc[m][n][j] + bv[n]));
            }
        }
    }
#undef PHASE
#undef STAGE_A
#undef STAGE_B
}

extern "C" void kernel_launch(void* const* d_in, const int* in_sizes, int n_in,
                              void* d_out, int out_size, void* d_ws, size_t ws_size,
                              hipStream_t stream) {
    const float* x  = (const float*)d_in[0];
    const float* y  = (const float*)d_in[1];
    const float* We = (const float*)d_in[2];
    const float* be = (const float*)d_in[3];
    const float* Wg = (const float*)d_in[4];
    const float* bg = (const float*)d_in[5];
    float* out = (float*)d_out;

    char* ws = (char*)d_ws;
    int*   meta  = (int*)ws;                               // [0..7] counts, [8..15] offsets
    int*   hist  = (int*)(ws + 256);                       // [64*8]
    int*   cbase = (int*)(ws + 256 + 2048);                // [64*8]
    int*   tkidx = (int*)(ws + 8192);                      // [NB*2]
    float* tkg   = (float*)(ws + 8192 + 65536);            // [NB*2]
    int*   tok   = (int*)(ws + 8192 + 2 * 65536);          // [NB*2]
    float* gat   = (float*)(ws + 8192 + 3 * 65536);        // [NB*2]
    unsigned short* inpb = (unsigned short*)(ws + 8192 + 4 * 65536);
    unsigned short* wb   = (unsigned short*)(ws + 8192 + 4 * 65536 + (size_t)NB * ND * 2);

    (void)hipMemsetAsync(d_out, 0, (size_t)NB * ND * sizeof(float), stream);
    cvt_w_kernel<<<16384, 256, 0, stream>>>(We, wb);
    gatecvt_kernel<<<2048, 256, 0, stream>>>(x, y, Wg, bg, inpb, tkidx, tkg);
    hist_kernel<<<64, 256, 0, stream>>>(tkidx, hist);
    scan_kernel<<<1, 64, 0, stream>>>(hist, cbase, meta);
    fill_kernel<<<64, 256, 0, stream>>>(tkidx, tkg, cbase, tok, gat);
    moe_gemm_kernel<<<dim3(8, 32, 8), 512, 0, stream>>>(inpb, wb, be, tok, gat, meta, out);
}

// Round 5
// 334.006 us; speedup vs baseline: 1.9279x; 1.0740x over previous
//
#include <hip/hip_runtime.h>
#include <stdint.h>

typedef __attribute__((ext_vector_type(4))) float f32x4;
typedef __attribute__((ext_vector_type(8))) short short8v;
typedef __attribute__((ext_vector_type(8))) unsigned short ushort8v;
typedef __attribute__((ext_vector_type(4))) unsigned short ushort4v;

#define NB 8192
#define ND 2048
#define NE 8
#define NT 32   // K-tiles of 64

__device__ __forceinline__ unsigned short f2bf(float f) {
    union { float f; uint32_t u; } c; c.f = f;
    uint32_t u = c.u;
    u = u + 0x7FFFu + ((u >> 16) & 1u);   // RNE
    return (unsigned short)(u >> 16);
}

// ---- convert W_experts fp32 -> bf16 ----
__global__ __launch_bounds__(256) void cvt_w_kernel(const float* __restrict__ W,
                                                    unsigned short* __restrict__ Wb) {
    size_t i = ((size_t)blockIdx.x * 256 + threadIdx.x) * 8;
    float4 a = *(const float4*)(W + i);
    float4 b = *(const float4*)(W + i + 4);
    ushort8v o;
    o[0] = f2bf(a.x); o[1] = f2bf(a.y); o[2] = f2bf(a.z); o[3] = f2bf(a.w);
    o[4] = f2bf(b.x); o[5] = f2bf(b.y); o[6] = f2bf(b.z); o[7] = f2bf(b.w);
    *(ushort8v*)(Wb + i) = o;
}

// ---- fused: inp=concat(x,y)->bf16  +  fp64 gate logits -> top2 + softmax ----
__global__ __launch_bounds__(256) void gatecvt_kernel(const float* __restrict__ x,
                                                      const float* __restrict__ y,
                                                      const float* __restrict__ Wg,
                                                      const float* __restrict__ bg,
                                                      unsigned short* __restrict__ inpb,
                                                      int* __restrict__ tkidx,
                                                      float* __restrict__ tkg) {
    const int wave = threadIdx.x >> 6, lane = threadIdx.x & 63;
    const int b = blockIdx.x * 4 + wave;
    const float* xb = x + (size_t)b * 1024;
    const float* yb = y + (size_t)b * 1024;
    unsigned short* ob = inpb + (size_t)b * ND;
    double acc[NE] = {0, 0, 0, 0, 0, 0, 0, 0};
#pragma unroll
    for (int it = 0; it < 8; it++) {
        const int d = it * 256 + lane * 4;
        float4 v = (it < 4) ? *(const float4*)(xb + d) : *(const float4*)(yb + (d - 1024));
        ushort4v o;
        o[0] = f2bf(v.x); o[1] = f2bf(v.y); o[2] = f2bf(v.z); o[3] = f2bf(v.w);
        *(ushort4v*)(ob + d) = o;
#pragma unroll
        for (int e = 0; e < NE; e++) {
            float4 w = *(const float4*)(Wg + e * ND + d);
            acc[e] += (double)v.x * (double)w.x + (double)v.y * (double)w.y
                    + (double)v.z * (double)w.z + (double)v.w * (double)w.w;
        }
    }
#pragma unroll
    for (int e = 0; e < NE; e++) {
        double s = acc[e];
#pragma unroll
        for (int o = 32; o >= 1; o >>= 1) s += __shfl_xor(s, o, 64);
        acc[e] = s;
    }
    if (lane == 0) {
        double v0 = -1e300, v1 = -1e300; int i0 = 0, i1 = 1;
#pragma unroll
        for (int e = 0; e < NE; e++) {
            double val = acc[e] + (double)bg[e];
            if (val > v0)      { v1 = v0; i1 = i0; v0 = val; i0 = e; }
            else if (val > v1) { v1 = val; i1 = e; }
        }
        double e1 = exp(v1 - v0);
        double inv = 1.0 / (1.0 + e1);
        tkidx[b * 2]     = i0;
        tkidx[b * 2 + 1] = i1;
        tkg[b * 2]       = (float)inv;
        tkg[b * 2 + 1]   = (float)(e1 * inv);
    }
}

// ---- per-chunk histogram via ballot (64 chunks x 256 pairs), deterministic ----
__global__ __launch_bounds__(256) void hist_kernel(const int* __restrict__ tkidx,
                                                   int* __restrict__ hist) {
    const int p = blockIdx.x * 256 + threadIdx.x;
    const int wave = threadIdx.x >> 6, lane = threadIdx.x & 63;
    const int e = tkidx[p];
    __shared__ int cnt[4][8];
#pragma unroll
    for (int e2 = 0; e2 < 8; e2++) {
        unsigned long long m = __ballot(e == e2);
        if (lane == e2) cnt[wave][e2] = __popcll(m);
    }
    __syncthreads();
    if (threadIdx.x < 8)
        hist[blockIdx.x * 8 + threadIdx.x] =
            cnt[0][threadIdx.x] + cnt[1][threadIdx.x] + cnt[2][threadIdx.x] + cnt[3][threadIdx.x];
}

// ---- scan: chunk bases + expert totals/offsets ----
__global__ void scan_kernel(const int* __restrict__ hist, int* __restrict__ chunkbase,
                            int* __restrict__ meta) {
    __shared__ int total[8], off[8];
    const int t = threadIdx.x;
    if (t < 8) {
        int run = 0;
        for (int c = 0; c < 64; c++) { chunkbase[c * 8 + t] = run; run += hist[c * 8 + t]; }
        total[t] = run; meta[t] = run;
    }
    __syncthreads();
    if (t == 0) { int o = 0; for (int e = 0; e < 8; e++) { off[e] = o; meta[8 + e] = o; o += total[e]; } }
    __syncthreads();
    for (int i = t; i < 512; i += 64) chunkbase[i] += off[i & 7];
}

// ---- fill: stable rank within (chunk,expert) via ballot, no atomics ----
__global__ __launch_bounds__(256) void fill_kernel(const int* __restrict__ tkidx,
                                                   const float* __restrict__ tkg,
                                                   const int* __restrict__ chunkbase,
                                                   int* __restrict__ tok,
                                                   float* __restrict__ gat) {
    const int p = blockIdx.x * 256 + threadIdx.x;
    const int wave = threadIdx.x >> 6, lane = threadIdx.x & 63;
    const int e = tkidx[p];
    const float g = tkg[p];
    __shared__ int cnt[4][8];
    unsigned long long mym = 0;
#pragma unroll
    for (int e2 = 0; e2 < 8; e2++) {
        unsigned long long m = __ballot(e == e2);
        if (e == e2) mym = m;
        if (lane == e2) cnt[wave][e2] = __popcll(m);
    }
    __syncthreads();
    int basep = chunkbase[blockIdx.x * 8 + e];
    for (int w = 0; w < wave; w++) basep += cnt[w][e];
    const int rank = __popcll(mym & ((1ull << lane) - 1ull));
    tok[basep + rank] = p >> 1;
    gat[basep + rank] = g;
}

#define GLD16(gp, lp) __builtin_amdgcn_global_load_lds( \
    (const __attribute__((address_space(1))) uint32_t*)(gp), \
    (__attribute__((address_space(3))) uint32_t*)(lp), 16, 0, 0)

// ================= grouped expert GEMM, 8-phase read-once schedule =================
// 256x256 tile, BK=64, 8 waves (2M x 4N). LDS: 2 bufs x 4 half-slots (A0,A1,B0,B1).
// Output mapping: row(m) = (m>>2)*128 + wr*64 + (m&3)*16 ; col(n) = (n>>1)*128 + wcn*32 + (n&1)*16
// READ-ONCE phases (24 ds_read_b128 / K-tile / wave — LDS pipe is the binding constraint):
//   P0: load A0+B(ks0), MFMA mq0/ks0   P1: load A1, REUSE B regs, MFMA mq1/ks0
//   P2: load A0+B(ks1), MFMA mq0/ks1   P3: load A1, reuse, MFMA mq1/ks1
// Stages: P0->A1(nb,t+1), P1->B0(nb,t+1), P2->B1(nb,t+1), P3->A0(buf,t+2) [A0 last read @P2;
// P3 starts after P2's end-barrier => race-free]. Checkpoint vmcnt(2) guarantees ALL four
// halves that t+1 reads at P0/P1; leaves A0(t+2)'s 2 loads in flight.
__global__ __launch_bounds__(512, 2) void moe_gemm_kernel(
    const unsigned short* __restrict__ Ab,   // [NB][ND] bf16
    const unsigned short* __restrict__ Wb,   // [NE][ND][ND] bf16 (out-major)
    const float* __restrict__ bias,          // [NE][ND]
    const int* __restrict__ tok,             // [2*NB] token ids, expert-bucketed
    const float* __restrict__ gat,           // [2*NB] gate weights
    const int* __restrict__ meta,            // [0..7] counts, [8..15] offsets
    float* __restrict__ out)                 // [NB][ND] fp32, pre-zeroed
{
    const int e = blockIdx.z;
    const int cnt = meta[e];
    const int row0 = blockIdx.y * 256;
    if (row0 >= cnt) return;
    const int col0 = blockIdx.x * 256;
    const int base = meta[8 + e];

    // [buf][half: 0=A0 1=A1 2=B0 3=B1][128 rows][64 cols] = 128 KB
    __shared__ __align__(16) unsigned short S[2][4][128][64];

    const int tid  = threadIdx.x;
    const int wv   = tid >> 6;
    const int lane = tid & 63;
    const int wr = wv >> 2, wcn = wv & 3;
    const int fr = lane & 15, kh = lane >> 4;

    // --- staging source pointers (linear LDS dest + inverse-swizzled global chunk)
    const int srow = tid >> 3;                         // 0..63 per round
    const int cg8  = ((tid & 7) ^ (srow & 7)) * 8;     // swizzled source chunk (shorts)
    const unsigned short* wbase = Wb + (size_t)e * ND * ND;
    const unsigned short* aptr[2][2];
    const unsigned short* bptr[2][2];
#pragma unroll
    for (int h = 0; h < 2; h++)
#pragma unroll
        for (int i = 0; i < 2; i++) {
            int rt = h * 128 + i * 64 + srow;
            int gr = row0 + rt; if (gr > cnt - 1) gr = cnt - 1;
            aptr[h][i] = Ab + (size_t)tok[base + gr] * ND + cg8;
            bptr[h][i] = wbase + (size_t)(col0 + rt) * ND + cg8;
        }

#define STAGE_A(SB, SM, SK) do { \
    GLD16(aptr[SM][0] + (SK), (char*)&S[SB][SM][0][0] + tid * 16); \
    GLD16(aptr[SM][1] + (SK), (char*)&S[SB][SM][0][0] + tid * 16 + 8192); } while (0)
#define STAGE_B(SB, SN, SK) do { \
    GLD16(bptr[SN][0] + (SK), (char*)&S[SB][2 + SN][0][0] + tid * 16); \
    GLD16(bptr[SN][1] + (SK), (char*)&S[SB][2 + SN][0][0] + tid * 16 + 8192); } while (0)

    f32x4 acc[8][4];
#pragma unroll
    for (int m = 0; m < 8; m++)
#pragma unroll
        for (int n = 0; n < 4; n++) acc[m][n] = f32x4{0.f, 0.f, 0.f, 0.f};

    const int arow = wr * 64 + fr;        // + ml*16 within A-half
    int ca[2];
#pragma unroll
    for (int ks = 0; ks < 2; ks++) ca[ks] = ((ks * 4 + kh) ^ (fr & 7)) * 8;

    short8v br[4];   // B fragments, persist across the two mq-phases of one ks

#define PH_FULL(PB, PM, KS, ...) do { \
    short8v ar[4]; \
    _Pragma("unroll") \
    for (int ml = 0; ml < 4; ml++) \
        ar[ml] = *(const short8v*)&S[PB][PM][arow + ml * 16][ca[KS]]; \
    _Pragma("unroll") \
    for (int n = 0; n < 4; n++) \
        br[n] = *(const short8v*)&S[PB][2 + (n >> 1)][wcn * 32 + (n & 1) * 16 + fr][ca[KS]]; \
    __VA_ARGS__; \
    __builtin_amdgcn_sched_barrier(0); \
    __builtin_amdgcn_s_barrier(); \
    asm volatile("s_waitcnt lgkmcnt(0)" ::: "memory"); \
    __builtin_amdgcn_sched_barrier(0); \
    __builtin_amdgcn_s_setprio(1); \
    _Pragma("unroll") \
    for (int ml = 0; ml < 4; ml++) \
        _Pragma("unroll") \
        for (int n = 0; n < 4; n++) \
            acc[PM * 4 + ml][n] = __builtin_amdgcn_mfma_f32_16x16x32_bf16( \
                ar[ml], br[n], acc[PM * 4 + ml][n], 0, 0, 0); \
    __builtin_amdgcn_s_setprio(0); \
    __builtin_amdgcn_sched_barrier(0); \
    __builtin_amdgcn_s_barrier(); \
} while (0)

#define PH_REUSE(PB, PM, KS, ...) do { \
    short8v ar[4]; \
    _Pragma("unroll") \
    for (int ml = 0; ml < 4; ml++) \
        ar[ml] = *(const short8v*)&S[PB][PM][arow + ml * 16][ca[KS]]; \
    __VA_ARGS__; \
    __builtin_amdgcn_sched_barrier(0); \
    __builtin_amdgcn_s_barrier(); \
    asm volatile("s_waitcnt lgkmcnt(0)" ::: "memory"); \
    __builtin_amdgcn_sched_barrier(0); \
    __builtin_amdgcn_s_setprio(1); \
    _Pragma("unroll") \
    for (int ml = 0; ml < 4; ml++) \
        _Pragma("unroll") \
        for (int n = 0; n < 4; n++) \
            acc[PM * 4 + ml][n] = __builtin_amdgcn_mfma_f32_16x16x32_bf16( \
                ar[ml], br[n], acc[PM * 4 + ml][n], 0, 0, 0); \
    __builtin_amdgcn_s_setprio(0); \
    __builtin_amdgcn_sched_barrier(0); \
    __builtin_amdgcn_s_barrier(); \
} while (0)

    // --- prologue: tile0 all halves + tile1 A0 (the distance-2 seed)
    STAGE_A(0, 0, 0);
    STAGE_B(0, 0, 0);
    STAGE_B(0, 1, 0);
    STAGE_A(0, 1, 0);
    STAGE_A(1, 0, 64);
    asm volatile("s_waitcnt vmcnt(2)" ::: "memory");
    __builtin_amdgcn_sched_barrier(0);
    __builtin_amdgcn_s_barrier();

    int buf = 0;
    for (int t = 0; t < NT; t++) {
        const int nb = buf ^ 1;
        const int kt1 = (t + 1) * 64;
        const int kt2 = (t + 2) * 64;
        PH_FULL (buf, 0, 0, { if (t + 1 < NT) STAGE_A(nb, 1, kt1); });
        PH_REUSE(buf, 1, 0, { if (t + 1 < NT) STAGE_B(nb, 0, kt1); });
        PH_FULL (buf, 0, 1, { if (t + 1 < NT) STAGE_B(nb, 1, kt1); });
        PH_REUSE(buf, 1, 1, { if (t + 2 < NT) STAGE_A(buf, 0, kt2); });
        if (t + 1 < NT) {
            if (t == NT - 2) asm volatile("s_waitcnt vmcnt(0)" ::: "memory");
            else             asm volatile("s_waitcnt vmcnt(2)" ::: "memory");
            __builtin_amdgcn_sched_barrier(0);
            __builtin_amdgcn_s_barrier();
        }
        buf = nb;
    }

    // --- epilogue: gate-weighted scatter-add (exactly 2 adds/output element) ---
    int   coln[4];
    float bv[4];
#pragma unroll
    for (int n = 0; n < 4; n++) {
        coln[n] = col0 + (n >> 1) * 128 + wcn * 32 + (n & 1) * 16 + fr;
        bv[n] = bias[e * ND + coln[n]];
    }
#pragma unroll
    for (int m = 0; m < 8; m++) {
        const int rbase = row0 + (m >> 2) * 128 + wr * 64 + (m & 3) * 16 + kh * 4;
#pragma unroll
        for (int j = 0; j < 4; j++) {
            const int R = rbase + j;
            if (R < cnt) {
                const int tkn = tok[base + R];
                const float g = gat[base + R];
                float* orow = out + (size_t)tkn * ND;
#pragma unroll
                for (int n = 0; n < 4; n++)
                    atomicAdd(orow + coln[n], g * (acc[m][n][j] + bv[n]));
            }
        }
    }
#undef PH_FULL
#undef PH_REUSE
#undef STAGE_A
#undef STAGE_B
}

extern "C" void kernel_launch(void* const* d_in, const int* in_sizes, int n_in,
                              void* d_out, int out_size, void* d_ws, size_t ws_size,
                              hipStream_t stream) {
    const float* x  = (const float*)d_in[0];
    const float* y  = (const float*)d_in[1];
    const float* We = (const float*)d_in[2];
    const float* be = (const float*)d_in[3];
    const float* Wg = (const float*)d_in[4];
    const float* bg = (const float*)d_in[5];
    float* out = (float*)d_out;

    char* ws = (char*)d_ws;
    int*   meta  = (int*)ws;                               // [0..7] counts, [8..15] offsets
    int*   hist  = (int*)(ws + 256);                       // [64*8]
    int*   cbase = (int*)(ws + 256 + 2048);                // [64*8]
    int*   tkidx = (int*)(ws + 8192);                      // [NB*2]
    float* tkg   = (float*)(ws + 8192 + 65536);            // [NB*2]
    int*   tok   = (int*)(ws + 8192 + 2 * 65536);          // [NB*2]
    float* gat   = (float*)(ws + 8192 + 3 * 65536);        // [NB*2]
    unsigned short* inpb = (unsigned short*)(ws + 8192 + 4 * 65536);
    unsigned short* wb   = (unsigned short*)(ws + 8192 + 4 * 65536 + (size_t)NB * ND * 2);

    (void)hipMemsetAsync(d_out, 0, (size_t)NB * ND * sizeof(float), stream);
    cvt_w_kernel<<<16384, 256, 0, stream>>>(We, wb);
    gatecvt_kernel<<<2048, 256, 0, stream>>>(x, y, Wg, bg, inpb, tkidx, tkg);
    hist_kernel<<<64, 256, 0, stream>>>(tkidx, hist);
    scan_kernel<<<1, 64, 0, stream>>>(hist, cbase, meta);
    fill_kernel<<<64, 256, 0, stream>>>(tkidx, tkg, cbase, tok, gat);
    moe_gemm_kernel<<<dim3(8, 32, 8), 512, 0, stream>>>(inpb, wb, be, tok, gat, meta, out);
}

// Round 6
// 305.190 us; speedup vs baseline: 2.1099x; 1.0944x over previous
//
#include <hip/hip_runtime.h>
#include <stdint.h>

typedef __attribute__((ext_vector_type(4))) float f32x4;
typedef __attribute__((ext_vector_type(8))) short short8v;
typedef __attribute__((ext_vector_type(8))) unsigned short ushort8v;
typedef __attribute__((ext_vector_type(4))) unsigned short ushort4v;

#define NB 8192
#define ND 2048
#define NE 8
#define NT 32   // K-tiles of 64

__device__ __forceinline__ unsigned short f2bf(float f) {
    union { float f; uint32_t u; } c; c.f = f;
    uint32_t u = c.u;
    u = u + 0x7FFFu + ((u >> 16) & 1u);   // RNE
    return (unsigned short)(u >> 16);
}

// ---- convert W_experts fp32 -> bf16 ----
__global__ __launch_bounds__(256) void cvt_w_kernel(const float* __restrict__ W,
                                                    unsigned short* __restrict__ Wb) {
    size_t i = ((size_t)blockIdx.x * 256 + threadIdx.x) * 8;
    float4 a = *(const float4*)(W + i);
    float4 b = *(const float4*)(W + i + 4);
    ushort8v o;
    o[0] = f2bf(a.x); o[1] = f2bf(a.y); o[2] = f2bf(a.z); o[3] = f2bf(a.w);
    o[4] = f2bf(b.x); o[5] = f2bf(b.y); o[6] = f2bf(b.z); o[7] = f2bf(b.w);
    *(ushort8v*)(Wb + i) = o;
}

// ---- fused: inp=concat(x,y)->bf16  +  fp64 gate logits -> top2 + softmax ----
__global__ __launch_bounds__(256) void gatecvt_kernel(const float* __restrict__ x,
                                                      const float* __restrict__ y,
                                                      const float* __restrict__ Wg,
                                                      const float* __restrict__ bg,
                                                      unsigned short* __restrict__ inpb,
                                                      int* __restrict__ tkidx,
                                                      float* __restrict__ tkg) {
    const int wave = threadIdx.x >> 6, lane = threadIdx.x & 63;
    const int b = blockIdx.x * 4 + wave;
    const float* xb = x + (size_t)b * 1024;
    const float* yb = y + (size_t)b * 1024;
    unsigned short* ob = inpb + (size_t)b * ND;
    double acc[NE] = {0, 0, 0, 0, 0, 0, 0, 0};
#pragma unroll
    for (int it = 0; it < 8; it++) {
        const int d = it * 256 + lane * 4;
        float4 v = (it < 4) ? *(const float4*)(xb + d) : *(const float4*)(yb + (d - 1024));
        ushort4v o;
        o[0] = f2bf(v.x); o[1] = f2bf(v.y); o[2] = f2bf(v.z); o[3] = f2bf(v.w);
        *(ushort4v*)(ob + d) = o;
#pragma unroll
        for (int e = 0; e < NE; e++) {
            float4 w = *(const float4*)(Wg + e * ND + d);
            acc[e] += (double)v.x * (double)w.x + (double)v.y * (double)w.y
                    + (double)v.z * (double)w.z + (double)v.w * (double)w.w;
        }
    }
#pragma unroll
    for (int e = 0; e < NE; e++) {
        double s = acc[e];
#pragma unroll
        for (int o = 32; o >= 1; o >>= 1) s += __shfl_xor(s, o, 64);
        acc[e] = s;
    }
    if (lane == 0) {
        double v0 = -1e300, v1 = -1e300; int i0 = 0, i1 = 1;
#pragma unroll
        for (int e = 0; e < NE; e++) {
            double val = acc[e] + (double)bg[e];
            if (val > v0)      { v1 = v0; i1 = i0; v0 = val; i0 = e; }
            else if (val > v1) { v1 = val; i1 = e; }
        }
        double e1 = exp(v1 - v0);
        double inv = 1.0 / (1.0 + e1);
        tkidx[b * 2]     = i0;
        tkidx[b * 2 + 1] = i1;
        tkg[b * 2]       = (float)inv;
        tkg[b * 2 + 1]   = (float)(e1 * inv);
    }
}

// ---- per-chunk histogram via ballot (64 chunks x 256 pairs), deterministic ----
__global__ __launch_bounds__(256) void hist_kernel(const int* __restrict__ tkidx,
                                                   int* __restrict__ hist) {
    const int p = blockIdx.x * 256 + threadIdx.x;
    const int wave = threadIdx.x >> 6, lane = threadIdx.x & 63;
    const int e = tkidx[p];
    __shared__ int cnt[4][8];
#pragma unroll
    for (int e2 = 0; e2 < 8; e2++) {
        unsigned long long m = __ballot(e == e2);
        if (lane == e2) cnt[wave][e2] = __popcll(m);
    }
    __syncthreads();
    if (threadIdx.x < 8)
        hist[blockIdx.x * 8 + threadIdx.x] =
            cnt[0][threadIdx.x] + cnt[1][threadIdx.x] + cnt[2][threadIdx.x] + cnt[3][threadIdx.x];
}

// ---- scan: chunk bases + expert totals/offsets ----
__global__ void scan_kernel(const int* __restrict__ hist, int* __restrict__ chunkbase,
                            int* __restrict__ meta) {
    __shared__ int total[8], off[8];
    const int t = threadIdx.x;
    if (t < 8) {
        int run = 0;
        for (int c = 0; c < 64; c++) { chunkbase[c * 8 + t] = run; run += hist[c * 8 + t]; }
        total[t] = run; meta[t] = run;
    }
    __syncthreads();
    if (t == 0) { int o = 0; for (int e = 0; e < 8; e++) { off[e] = o; meta[8 + e] = o; o += total[e]; } }
    __syncthreads();
    for (int i = t; i < 512; i += 64) chunkbase[i] += off[i & 7];
}

// ---- fill: stable rank within (chunk,expert) via ballot, no atomics ----
// stores the PAIR index p = (token<<1)|k so the GEMM knows which of the
// token's two experts this entry is (k selects the store destination).
__global__ __launch_bounds__(256) void fill_kernel(const int* __restrict__ tkidx,
                                                   const float* __restrict__ tkg,
                                                   const int* __restrict__ chunkbase,
                                                   int* __restrict__ tok,
                                                   float* __restrict__ gat) {
    const int p = blockIdx.x * 256 + threadIdx.x;
    const int wave = threadIdx.x >> 6, lane = threadIdx.x & 63;
    const int e = tkidx[p];
    const float g = tkg[p];
    __shared__ int cnt[4][8];
    unsigned long long mym = 0;
#pragma unroll
    for (int e2 = 0; e2 < 8; e2++) {
        unsigned long long m = __ballot(e == e2);
        if (e == e2) mym = m;
        if (lane == e2) cnt[wave][e2] = __popcll(m);
    }
    __syncthreads();
    int basep = chunkbase[blockIdx.x * 8 + e];
    for (int w = 0; w < wave; w++) basep += cnt[w][e];
    const int rank = __popcll(mym & ((1ull << lane) - 1ull));
    tok[basep + rank] = p;
    gat[basep + rank] = g;
}

// ---- combine: out += part1 (both fully written by the GEMM's plain stores) ----
__global__ __launch_bounds__(256) void combine_kernel(float* __restrict__ out,
                                                      const float* __restrict__ part1) {
    const size_t stride = (size_t)gridDim.x * 256 * 4;
    for (size_t i = ((size_t)blockIdx.x * 256 + threadIdx.x) * 4;
         i < (size_t)NB * ND; i += stride) {
        f32x4 a = *(const f32x4*)(out + i);
        f32x4 b = *(const f32x4*)(part1 + i);
        a = a + b;
        *(f32x4*)(out + i) = a;
    }
}

#define GLD16(gp, lp) __builtin_amdgcn_global_load_lds( \
    (const __attribute__((address_space(1))) uint32_t*)(gp), \
    (__attribute__((address_space(3))) uint32_t*)(lp), 16, 0, 0)

// ================= grouped expert GEMM, 8-phase read-once schedule =================
// 256x256 tile, BK=64, 8 waves (2M x 4N). LDS: 2 bufs x 4 half-slots (A0,A1,B0,B1).
// Read-once phases (24 ds_read_b128 / K-tile / wave):
//   P0: load A0+B(ks0), MFMA mq0/ks0; stage A1,B0,B1(t+1)->nb  [4-phase latency cover]
//   P1: load A1, reuse B regs, MFMA mq1/ks0
//   P2: load A0+B(ks1), MFMA mq0/ks1
//   P3: load A1, reuse, MFMA mq1/ks1; stage A0(t+2)->buf [A0 slot last read @P2]
// Checkpoint vmcnt(2): all four halves of t+1 landed; A0(t+2)'s 2 loads in flight.
// Epilogue: STORE mode = plain stores (k=0 -> out0, k=1 -> out1), race-free since each
// (token,k) appears in exactly one expert bucket; else atomicAdd fallback.
template <bool STORE>
__global__ __launch_bounds__(512, 2) void moe_gemm_kernel(
    const unsigned short* __restrict__ Ab,   // [NB][ND] bf16
    const unsigned short* __restrict__ Wb,   // [NE][ND][ND] bf16 (out-major)
    const float* __restrict__ bias,          // [NE][ND]
    const int* __restrict__ tok,             // [2*NB] packed (token<<1)|k, expert-bucketed
    const float* __restrict__ gat,           // [2*NB] gate weights
    const int* __restrict__ meta,            // [0..7] counts, [8..15] offsets
    float* __restrict__ out0,                // k=0 destination (d_out)
    float* __restrict__ out1)                // k=1 destination (part1; ==out0 in atomic mode)
{
    const int e = blockIdx.z;
    const int cnt = meta[e];
    const int row0 = blockIdx.y * 256;
    if (row0 >= cnt) return;
    const int col0 = blockIdx.x * 256;
    const int base = meta[8 + e];

    // [buf][half: 0=A0 1=A1 2=B0 3=B1][128 rows][64 cols] = 128 KB
    __shared__ __align__(16) unsigned short S[2][4][128][64];

    const int tid  = threadIdx.x;
    const int wv   = tid >> 6;
    const int lane = tid & 63;
    const int wr = wv >> 2, wcn = wv & 3;
    const int fr = lane & 15, kh = lane >> 4;

    // --- staging source pointers (linear LDS dest + inverse-swizzled global chunk)
    const int srow = tid >> 3;                         // 0..63 per round
    const int cg8  = ((tid & 7) ^ (srow & 7)) * 8;     // swizzled source chunk (shorts)
    const unsigned short* wbase = Wb + (size_t)e * ND * ND;
    const unsigned short* aptr[2][2];
    const unsigned short* bptr[2][2];
#pragma unroll
    for (int h = 0; h < 2; h++)
#pragma unroll
        for (int i = 0; i < 2; i++) {
            int rt = h * 128 + i * 64 + srow;
            int gr = row0 + rt; if (gr > cnt - 1) gr = cnt - 1;
            aptr[h][i] = Ab + (size_t)(tok[base + gr] >> 1) * ND + cg8;
            bptr[h][i] = wbase + (size_t)(col0 + rt) * ND + cg8;
        }

#define STAGE_A(SB, SM, SK) do { \
    GLD16(aptr[SM][0] + (SK), (char*)&S[SB][SM][0][0] + tid * 16); \
    GLD16(aptr[SM][1] + (SK), (char*)&S[SB][SM][0][0] + tid * 16 + 8192); } while (0)
#define STAGE_B(SB, SN, SK) do { \
    GLD16(bptr[SN][0] + (SK), (char*)&S[SB][2 + SN][0][0] + tid * 16); \
    GLD16(bptr[SN][1] + (SK), (char*)&S[SB][2 + SN][0][0] + tid * 16 + 8192); } while (0)

    f32x4 acc[8][4];
#pragma unroll
    for (int m = 0; m < 8; m++)
#pragma unroll
        for (int n = 0; n < 4; n++) acc[m][n] = f32x4{0.f, 0.f, 0.f, 0.f};

    const int arow = wr * 64 + fr;        // + ml*16 within A-half
    int ca[2];
#pragma unroll
    for (int ks = 0; ks < 2; ks++) ca[ks] = ((ks * 4 + kh) ^ (fr & 7)) * 8;

    short8v br[4];   // B fragments, persist across the two mq-phases of one ks

#define PH_FULL(PB, PM, KS, ...) do { \
    short8v ar[4]; \
    _Pragma("unroll") \
    for (int ml = 0; ml < 4; ml++) \
        ar[ml] = *(const short8v*)&S[PB][PM][arow + ml * 16][ca[KS]]; \
    _Pragma("unroll") \
    for (int n = 0; n < 4; n++) \
        br[n] = *(const short8v*)&S[PB][2 + (n >> 1)][wcn * 32 + (n & 1) * 16 + fr][ca[KS]]; \
    __VA_ARGS__; \
    __builtin_amdgcn_sched_barrier(0); \
    __builtin_amdgcn_s_barrier(); \
    asm volatile("s_waitcnt lgkmcnt(0)" ::: "memory"); \
    __builtin_amdgcn_sched_barrier(0); \
    __builtin_amdgcn_s_setprio(1); \
    _Pragma("unroll") \
    for (int ml = 0; ml < 4; ml++) \
        _Pragma("unroll") \
        for (int n = 0; n < 4; n++) \
            acc[PM * 4 + ml][n] = __builtin_amdgcn_mfma_f32_16x16x32_bf16( \
                ar[ml], br[n], acc[PM * 4 + ml][n], 0, 0, 0); \
    __builtin_amdgcn_s_setprio(0); \
    __builtin_amdgcn_sched_barrier(0); \
    __builtin_amdgcn_s_barrier(); \
} while (0)

#define PH_REUSE(PB, PM, KS, ...) do { \
    short8v ar[4]; \
    _Pragma("unroll") \
    for (int ml = 0; ml < 4; ml++) \
        ar[ml] = *(const short8v*)&S[PB][PM][arow + ml * 16][ca[KS]]; \
    __VA_ARGS__; \
    __builtin_amdgcn_sched_barrier(0); \
    __builtin_amdgcn_s_barrier(); \
    asm volatile("s_waitcnt lgkmcnt(0)" ::: "memory"); \
    __builtin_amdgcn_sched_barrier(0); \
    __builtin_amdgcn_s_setprio(1); \
    _Pragma("unroll") \
    for (int ml = 0; ml < 4; ml++) \
        _Pragma("unroll") \
        for (int n = 0; n < 4; n++) \
            acc[PM * 4 + ml][n] = __builtin_amdgcn_mfma_f32_16x16x32_bf16( \
                ar[ml], br[n], acc[PM * 4 + ml][n], 0, 0, 0); \
    __builtin_amdgcn_s_setprio(0); \
    __builtin_amdgcn_sched_barrier(0); \
    __builtin_amdgcn_s_barrier(); \
} while (0)

    // --- prologue: tile0 all halves + tile1 A0 (the distance-2 seed)
    STAGE_A(0, 0, 0);
    STAGE_B(0, 0, 0);
    STAGE_B(0, 1, 0);
    STAGE_A(0, 1, 0);
    STAGE_A(1, 0, 64);
    asm volatile("s_waitcnt vmcnt(2)" ::: "memory");
    __builtin_amdgcn_sched_barrier(0);
    __builtin_amdgcn_s_barrier();

    int buf = 0;
    for (int t = 0; t < NT; t++) {
        const int nb = buf ^ 1;
        const int kt1 = (t + 1) * 64;
        const int kt2 = (t + 2) * 64;
        PH_FULL (buf, 0, 0, { if (t + 1 < NT) { STAGE_A(nb, 1, kt1); STAGE_B(nb, 0, kt1); STAGE_B(nb, 1, kt1); } });
        PH_REUSE(buf, 1, 0, {});
        PH_FULL (buf, 0, 1, {});
        PH_REUSE(buf, 1, 1, { if (t + 2 < NT) STAGE_A(buf, 0, kt2); });
        if (t + 1 < NT) {
            if (t == NT - 2) asm volatile("s_waitcnt vmcnt(0)" ::: "memory");
            else             asm volatile("s_waitcnt vmcnt(2)" ::: "memory");
            __builtin_amdgcn_sched_barrier(0);
            __builtin_amdgcn_s_barrier();
        }
        buf = nb;
    }

    // --- epilogue ---
    int   coln[4];
    float bv[4];
#pragma unroll
    for (int n = 0; n < 4; n++) {
        coln[n] = col0 + (n >> 1) * 128 + wcn * 32 + (n & 1) * 16 + fr;
        bv[n] = bias[e * ND + coln[n]];
    }
#pragma unroll
    for (int m = 0; m < 8; m++) {
        const int rbase = row0 + (m >> 2) * 128 + wr * 64 + (m & 3) * 16 + kh * 4;
#pragma unroll
        for (int j = 0; j < 4; j++) {
            const int R = rbase + j;
            if (R < cnt) {
                const int pr = tok[base + R];
                const float g = gat[base + R];
                float* orow = ((STORE && (pr & 1)) ? out1 : out0) + (size_t)(pr >> 1) * ND;
#pragma unroll
                for (int n = 0; n < 4; n++) {
                    const float v = g * (acc[m][n][j] + bv[n]);
                    if (STORE) orow[coln[n]] = v;
                    else       atomicAdd(&orow[coln[n]], v);
                }
            }
        }
    }
#undef PH_FULL
#undef PH_REUSE
#undef STAGE_A
#undef STAGE_B
}

extern "C" void kernel_launch(void* const* d_in, const int* in_sizes, int n_in,
                              void* d_out, int out_size, void* d_ws, size_t ws_size,
                              hipStream_t stream) {
    const float* x  = (const float*)d_in[0];
    const float* y  = (const float*)d_in[1];
    const float* We = (const float*)d_in[2];
    const float* be = (const float*)d_in[3];
    const float* Wg = (const float*)d_in[4];
    const float* bg = (const float*)d_in[5];
    float* out = (float*)d_out;

    char* ws = (char*)d_ws;
    int*   meta  = (int*)ws;                               // [0..7] counts, [8..15] offsets
    int*   hist  = (int*)(ws + 256);                       // [64*8]
    int*   cbase = (int*)(ws + 256 + 2048);                // [64*8]
    int*   tkidx = (int*)(ws + 8192);                      // [NB*2]
    float* tkg   = (float*)(ws + 8192 + 65536);            // [NB*2]
    int*   tok   = (int*)(ws + 8192 + 2 * 65536);          // [NB*2]
    float* gat   = (float*)(ws + 8192 + 3 * 65536);        // [NB*2]
    const size_t off_inpb = 8192 + 4 * 65536;
    const size_t off_wb   = off_inpb + (size_t)NB * ND * 2;
    const size_t off_p1   = off_wb + (size_t)NE * ND * ND * 2;
    const size_t needed   = off_p1 + (size_t)NB * ND * 4;
    unsigned short* inpb = (unsigned short*)(ws + off_inpb);
    unsigned short* wb   = (unsigned short*)(ws + off_wb);
    float*          part1 = (float*)(ws + off_p1);
    const bool store_mode = (ws_size >= needed);

    cvt_w_kernel<<<16384, 256, 0, stream>>>(We, wb);
    gatecvt_kernel<<<2048, 256, 0, stream>>>(x, y, Wg, bg, inpb, tkidx, tkg);
    hist_kernel<<<64, 256, 0, stream>>>(tkidx, hist);
    scan_kernel<<<1, 64, 0, stream>>>(hist, cbase, meta);
    fill_kernel<<<64, 256, 0, stream>>>(tkidx, tkg, cbase, tok, gat);
    if (store_mode) {
        moe_gemm_kernel<true><<<dim3(8, 32, 8), 512, 0, stream>>>(inpb, wb, be, tok, gat, meta, out, part1);
        combine_kernel<<<2048, 256, 0, stream>>>(out, part1);
    } else {
        (void)hipMemsetAsync(d_out, 0, (size_t)NB * ND * sizeof(float), stream);
        moe_gemm_kernel<false><<<dim3(8, 32, 8), 512, 0, stream>>>(inpb, wb, be, tok, gat, meta, out, out);
    }
}